// Round 1
// baseline (290.830 us; speedup 1.0000x reference)
//
#include <hip/hip_runtime.h>

#define B_   16
#define CIN  32
#define COUT 32
#define H_   256
#define W_   256
#define IN_ZP  3
#define OUT_ZP (-5)
#define TH 4
#define TW 64
#define HW (H_ * W_)

#if defined(__has_builtin)
#if __has_builtin(__builtin_amdgcn_sdot4)
#define HAVE_SDOT4 1
#endif
#endif

__device__ __forceinline__ int dot4(int a, int b, int c) {
#ifdef HAVE_SDOT4
    return __builtin_amdgcn_sdot4(a, b, c, false);
#else
    c += ((a << 24) >> 24) * ((b << 24) >> 24);
    c += ((a << 16) >> 24) * ((b << 16) >> 24);
    c += ((a << 8)  >> 24) * ((b << 8)  >> 24);
    c += (a >> 24) * (b >> 24);
    return c;
#endif
}

// ws layout (ints): [0..2303] packed weights [co][cig][k], [2304..2335] shifted bias,
// [2336..2367] int_scale, [2368..2399] frac_bits
__global__ void qconv_prep(const int* __restrict__ qw, const int* __restrict__ qb,
                           const float* __restrict__ wscale, int* __restrict__ ws) {
    int tid = threadIdx.x;
    // pack weights: byte j of ws[co*72 + cig*9 + k] = qweight[co][cig*4+j][k]
    for (int idx = tid; idx < COUT * 8 * 9; idx += blockDim.x) {
        int co = idx / 72, rem = idx % 72;
        int cig = rem / 9, k = rem % 9;
        int base = co * (CIN * 9) + (cig * 4) * 9 + k;
        int b0 = qw[base]      & 0xff;
        int b1 = qw[base + 9]  & 0xff;
        int b2 = qw[base + 18] & 0xff;
        int b3 = qw[base + 27] & 0xff;
        ws[idx] = b0 | (b1 << 8) | (b2 << 16) | (b3 << 24);
    }
    if (tid < COUT) {
        int co = tid;
        int wsum = 0;
        for (int i = 0; i < CIN * 9; ++i) wsum += qw[co * (CIN * 9) + i];
        int sb = qb[co] - wsum * IN_ZP;
        // folded_scale = (0.02f * ws) / 0.05f, all in f32 like the reference
        float fs = (0.02f * wscale[co]) / 0.05f;
        float fb = floorf(log2f(127.0f / fs));
        int frac = (int)fb;
        int iscale = (int)rintf(fs * exp2f(fb));  // rint = half-to-even, matches jnp.round
        ws[2304 + co] = sb;
        ws[2336 + co] = iscale;
        ws[2368 + co] = frac;
    }
}

__global__ __launch_bounds__(256, 2) void qconv_main(const int* __restrict__ x,
                                                     const int* __restrict__ ws,
                                                     int* __restrict__ out) {
    // LDS: 8 ci-groups x (TH+2) x (TW+2) packed int8x4 taps
    __shared__ int smem[8][TH + 2][TW + 2];
    const int wt = blockIdx.x * TW;
    const int ht = blockIdx.y * TH;
    const int b  = blockIdx.z;
    const int tid = threadIdx.x;
    const int* xb = x + b * (CIN * HW);

    // stage x tile into LDS, packing 4 consecutive ci per dword; pad with IN_ZP
    for (int idx = tid; idx < 8 * (TH + 2) * (TW + 2); idx += 256) {
        int cig = idx / ((TH + 2) * (TW + 2));
        int rem = idx % ((TH + 2) * (TW + 2));
        int r = rem / (TW + 2), c = rem % (TW + 2);
        int gh = ht - 1 + r, gw = wt - 1 + c;
        int packed;
        if ((unsigned)gh < H_ && (unsigned)gw < W_) {
            const int* p = xb + (cig * 4) * HW + gh * W_ + gw;
            int v0 = p[0]      & 0xff;
            int v1 = p[HW]     & 0xff;
            int v2 = p[2 * HW] & 0xff;
            int v3 = p[3 * HW] & 0xff;
            packed = v0 | (v1 << 8) | (v2 << 16) | (v3 << 24);
        } else {
            packed = 0x03030303;  // 4x IN_ZP
        }
        ((int*)smem)[idx] = packed;
    }
    __syncthreads();

    const int row = tid >> 6, col = tid & 63;
    // load this thread's 72 packed taps into registers
    int xr[8][3][3];
#pragma unroll
    for (int cig = 0; cig < 8; ++cig)
#pragma unroll
        for (int r = 0; r < 3; ++r)
#pragma unroll
            for (int c = 0; c < 3; ++c)
                xr[cig][r][c] = smem[cig][row + r][col + c];

    const int* wq  = ws;
    const int* sb  = ws + 2304;
    const int* isc = ws + 2336;
    const int* fbp = ws + 2368;
    int* outp = out + ((b * COUT) * H_ + (ht + row)) * W_ + wt + col;

#pragma unroll 2
    for (int co = 0; co < COUT; ++co) {
        int acc = sb[co];
        const int* w = wq + co * 72;
#pragma unroll
        for (int cig = 0; cig < 8; ++cig) {
#pragma unroll
            for (int k = 0; k < 9; ++k)
                acc = dot4(xr[cig][k / 3][k % 3], w[cig * 9 + k], acc);
        }
        int t = (acc * isc[co]) >> fbp[co];  // int32 mul + arithmetic shift, per reference
        t += OUT_ZP;
        t = min(127, max(-128, t));
        outp[co * HW] = t;
    }
}

extern "C" void kernel_launch(void* const* d_in, const int* in_sizes, int n_in,
                              void* d_out, int out_size, void* d_ws, size_t ws_size,
                              hipStream_t stream) {
    const int*   x   = (const int*)d_in[0];
    const int*   qw  = (const int*)d_in[1];
    const int*   qb  = (const int*)d_in[2];
    const float* wsc = (const float*)d_in[3];
    int* ws  = (int*)d_ws;
    int* out = (int*)d_out;

    qconv_prep<<<1, 256, 0, stream>>>(qw, qb, wsc, ws);
    dim3 grid(W_ / TW, H_ / TH, B_);
    qconv_main<<<grid, 256, 0, stream>>>(x, ws, out);
}

// Round 2
// 289.839 us; speedup vs baseline: 1.0034x; 1.0034x over previous
//
#include <hip/hip_runtime.h>

#define B_   16
#define CIN  32
#define COUT 32
#define H_   256
#define W_   256
#define IN_ZP  3
#define OUT_ZP (-5)
#define TH 4
#define TW 64
#define HW (H_ * W_)

#if defined(__has_builtin)
#if __has_builtin(__builtin_amdgcn_sdot4)
#define HAVE_SDOT4 1
#endif
#endif

__device__ __forceinline__ int dot4(int a, int b, int c) {
#ifdef HAVE_SDOT4
    return __builtin_amdgcn_sdot4(a, b, c, false);
#else
    c += ((a << 24) >> 24) * ((b << 24) >> 24);
    c += ((a << 16) >> 24) * ((b << 16) >> 24);
    c += ((a << 8)  >> 24) * ((b << 8)  >> 24);
    c += (a >> 24) * (b >> 24);
    return c;
#endif
}

// ws layout (ints):
//   [0 .. 2303]    packed weights, layout [tap][co]: ws[(cig*9+k)*32 + co],
//                  byte j = qweight[co][cig*4+j][k]
//   [2304 .. 2335] shifted bias
//   [2336 .. 2367] int_scale
//   [2368 .. 2399] frac_bits
__global__ void qconv_prep(const int* __restrict__ qw, const int* __restrict__ qb,
                           const float* __restrict__ wscale, int* __restrict__ ws) {
    const int co  = blockIdx.x;   // 32 blocks
    const int tid = threadIdx.x;  // 256 threads
    __shared__ int red[4];
    const int* wco = qw + co * (CIN * 9);

    // parallel weight-sum reduction
    int s = 0;
    for (int i = tid; i < CIN * 9; i += 256) s += wco[i];
    for (int off = 32; off; off >>= 1) s += __shfl_down(s, off, 64);
    if ((tid & 63) == 0) red[tid >> 6] = s;

    // pack this co's 72 taps into [tap][co] layout
    if (tid < 72) {
        int cig = tid / 9, k = tid % 9;
        int base = co * (CIN * 9) + (cig * 4) * 9 + k;
        int b0 = qw[base]      & 0xff;
        int b1 = qw[base + 9]  & 0xff;
        int b2 = qw[base + 18] & 0xff;
        int b3 = qw[base + 27] & 0xff;
        ws[tid * 32 + co] = b0 | (b1 << 8) | (b2 << 16) | (b3 << 24);
    }
    __syncthreads();
    if (tid == 0) {
        int wsum = red[0] + red[1] + red[2] + red[3];
        ws[2304 + co] = qb[co] - wsum * IN_ZP;
        float fs = (0.02f * wscale[co]) / 0.05f;  // folded scale, f32 like reference
        float fb = floorf(log2f(127.0f / fs));
        ws[2336 + co] = (int)rintf(fs * exp2f(fb));  // half-to-even, matches jnp.round
        ws[2368 + co] = (int)fb;
    }
}

__global__ __launch_bounds__(256, 2) void qconv_main(const int* __restrict__ x,
                                                     const int* __restrict__ ws,
                                                     int* __restrict__ out) {
    // LDS: 8 ci-groups x (TH+2) x (TW+2) packed int8x4 taps
    __shared__ int smem[8][TH + 2][TW + 2];
    const int wt = blockIdx.x * TW;
    const int ht = blockIdx.y * TH;
    const int b  = blockIdx.z;
    const int tid = threadIdx.x;
    const int* xb = x + b * (CIN * HW);

    // stage x tile into LDS, packing 4 consecutive ci per dword; pad with IN_ZP
    for (int idx = tid; idx < 8 * (TH + 2) * (TW + 2); idx += 256) {
        int cig = idx / ((TH + 2) * (TW + 2));
        int rem = idx % ((TH + 2) * (TW + 2));
        int r = rem / (TW + 2), c = rem % (TW + 2);
        int gh = ht - 1 + r, gw = wt - 1 + c;
        int packed;
        if ((unsigned)gh < H_ && (unsigned)gw < W_) {
            const int* p = xb + (cig * 4) * HW + gh * W_ + gw;
            int v0 = p[0]      & 0xff;
            int v1 = p[HW]     & 0xff;
            int v2 = p[2 * HW] & 0xff;
            int v3 = p[3 * HW] & 0xff;
            packed = v0 | (v1 << 8) | (v2 << 16) | (v3 << 24);
        } else {
            packed = 0x03030303;  // 4x IN_ZP
        }
        ((int*)smem)[idx] = packed;
    }
    __syncthreads();

    const int row = tid >> 6, col = tid & 63;

    // 32 per-co accumulators live in VGPRs; taps are the outer loop.
    int acc[COUT];
    const int* sb = ws + 2304;
#pragma unroll
    for (int co = 0; co < COUT; ++co) acc[co] = sb[co];

#pragma unroll
    for (int cig = 0; cig < 8; ++cig) {
        int xv[9];
#pragma unroll
        for (int r = 0; r < 3; ++r)
#pragma unroll
            for (int c = 0; c < 3; ++c)
                xv[r * 3 + c] = smem[cig][row + r][col + c];
#pragma unroll
        for (int k = 0; k < 9; ++k) {
            const int* w = ws + (cig * 9 + k) * 32;  // wave-uniform -> s_load
#pragma unroll
            for (int co = 0; co < COUT; ++co)
                acc[co] = dot4(xv[k], w[co], acc[co]);
        }
    }

    const int* isc = ws + 2336;
    const int* fbp = ws + 2368;
    int* outp = out + ((b * COUT) * H_ + (ht + row)) * W_ + wt + col;
#pragma unroll
    for (int co = 0; co < COUT; ++co) {
        int t = (acc[co] * isc[co]) >> fbp[co];  // int32 mul + arithmetic shift
        t += OUT_ZP;
        t = min(127, max(-128, t));
        outp[co * HW] = t;
    }
}

extern "C" void kernel_launch(void* const* d_in, const int* in_sizes, int n_in,
                              void* d_out, int out_size, void* d_ws, size_t ws_size,
                              hipStream_t stream) {
    const int*   x   = (const int*)d_in[0];
    const int*   qw  = (const int*)d_in[1];
    const int*   qb  = (const int*)d_in[2];
    const float* wsc = (const float*)d_in[3];
    int* ws  = (int*)d_ws;
    int* out = (int*)d_out;

    qconv_prep<<<32, 256, 0, stream>>>(qw, qb, wsc, ws);
    dim3 grid(W_ / TW, H_ / TH, B_);
    qconv_main<<<grid, 256, 0, stream>>>(x, ws, out);
}

// Round 3
// 267.186 us; speedup vs baseline: 1.0885x; 1.0848x over previous
//
#include <hip/hip_runtime.h>

#define B_   16
#define CIN  32
#define COUT 32
#define H_   256
#define W_   256
#define IN_ZP  3
#define OUT_ZP (-5)
#define HW (H_ * W_)
#define TH 8
#define TW 64
#define SW 72   // staged width: gw = wt-4 .. wt+67 (aligned for int4 loads)
#define SH 10   // staged height: gh = ht-1 .. ht+8

using i32x4  = __attribute__((ext_vector_type(4))) int;
using i32x16 = __attribute__((ext_vector_type(16))) int;

// ws layout (ints):
//   [0 .. 2303]    B fragments: ws[(t*64+lane)*4+g], byte b =
//                  qweight[co=lane&31][ci=16*(lane>>5)+4g+b][tap t]
//   [2304 .. 2335] shifted bias
//   [2336 .. 2367] int_scale
//   [2368 .. 2399] frac_bits
__global__ void qconv_prep(const int* __restrict__ qw, const int* __restrict__ qb,
                           const float* __restrict__ wscale, int* __restrict__ ws) {
    const int co  = blockIdx.x;   // 32 blocks
    const int tid = threadIdx.x;  // 256 threads
    __shared__ int red[4];
    const int* wco = qw + co * (CIN * 9);

    // parallel weight-sum reduction
    int s = 0;
    for (int i = tid; i < CIN * 9; i += 256) s += wco[i];
    for (int off = 32; off; off >>= 1) s += __shfl_down(s, off, 64);
    if ((tid & 63) == 0) red[tid >> 6] = s;

    // fill 72 of the 2304 B-fragment ints per block
    if (tid < 72) {
        int gidx = blockIdx.x * 72 + tid;
        int g    = gidx & 3;
        int lane = (gidx >> 2) & 63;
        int t    = gidx >> 8;
        int wco2 = lane & 31;
        int ci0  = 16 * (lane >> 5) + 4 * g;
        const int* base = qw + wco2 * (CIN * 9);
        int b0 = base[(ci0 + 0) * 9 + t] & 0xff;
        int b1 = base[(ci0 + 1) * 9 + t] & 0xff;
        int b2 = base[(ci0 + 2) * 9 + t] & 0xff;
        int b3 = base[(ci0 + 3) * 9 + t] & 0xff;
        ws[gidx] = b0 | (b1 << 8) | (b2 << 16) | (b3 << 24);
    }
    __syncthreads();
    if (tid == 0) {
        int wsum = red[0] + red[1] + red[2] + red[3];
        ws[2304 + co] = qb[co] - wsum * IN_ZP;
        float fs = (0.02f * wscale[co]) / 0.05f;  // folded scale, f32 like reference
        float fb = floorf(log2f(127.0f / fs));
        ws[2336 + co] = (int)rintf(fs * exp2f(fb));  // half-to-even, matches jnp.round
        ws[2368 + co] = (int)fb;
    }
}

__global__ __launch_bounds__(256) void qconv_main(const int* __restrict__ x,
                                                  const int* __restrict__ ws,
                                                  int* __restrict__ out) {
    // packed int8x4 (4 consecutive ci) im2col tile
    __shared__ int smem[8][SH][SW];
    const int wt = blockIdx.x * TW;
    const int ht = blockIdx.y * TH;
    const int b  = blockIdx.z;
    const int tid = threadIdx.x;
    const int* xb = x + b * (CIN * HW);

    // ---- stage x tile into LDS, vectorized 16B loads ----
    for (int idx = tid; idx < 8 * SH * (SW / 4); idx += 256) {
        int cig = idx / (SH * 18);
        int rem = idx % (SH * 18);
        int r = rem / 18, c4 = rem % 18;
        int gh  = ht - 1 + r;
        int gw0 = wt - 4 + c4 * 4;
        int pk[4];
        if ((unsigned)gh < H_ && gw0 >= 0 && gw0 + 3 < W_) {
            const int* p = xb + (cig * 4) * HW + gh * W_ + gw0;
            i32x4 v0 = *(const i32x4*)(p);
            i32x4 v1 = *(const i32x4*)(p + HW);
            i32x4 v2 = *(const i32x4*)(p + 2 * HW);
            i32x4 v3 = *(const i32x4*)(p + 3 * HW);
#pragma unroll
            for (int j = 0; j < 4; ++j)
                pk[j] = (v0[j] & 0xff) | ((v1[j] & 0xff) << 8) |
                        ((v2[j] & 0xff) << 16) | (v3[j] << 24);
        } else {
#pragma unroll
            for (int j = 0; j < 4; ++j) {
                int gw = gw0 + j;
                int b0 = 3, b1 = 3, b2 = 3, b3 = 3;
                if ((unsigned)gh < H_ && (unsigned)gw < W_) {
                    const int* p = xb + (cig * 4) * HW + gh * W_ + gw;
                    b0 = p[0] & 0xff; b1 = p[HW] & 0xff;
                    b2 = p[2 * HW] & 0xff; b3 = p[3 * HW] & 0xff;
                }
                pk[j] = b0 | (b1 << 8) | (b2 << 16) | (b3 << 24);
            }
        }
#pragma unroll
        for (int j = 0; j < 4; ++j) smem[cig][r][c4 * 4 + j] = pk[j];
    }
    __syncthreads();

    const int lane = tid & 63;
    const int wv   = tid >> 6;
    const int co   = lane & 31;
    const int hh   = lane >> 5;

    // preload the 9 B fragments (shared by all waves, L2-resident)
    i32x4 bfrag[9];
    const i32x4* bws = (const i32x4*)ws;
#pragma unroll
    for (int t = 0; t < 9; ++t) bfrag[t] = bws[t * 64 + lane];

    const int sb  = ws[2304 + co];
    const int isc = ws[2336 + co];
    const int fb  = ws[2368 + co];

    // 16 M-tiles of 32 pixels (8 rows x 2 w-chunks); 4 per wave
#pragma unroll
    for (int i = 0; i < 4; ++i) {
        int mt = wv * 4 + i;
        int r0 = mt >> 1, chunk = mt & 1;
        i32x16 acc;
#pragma unroll
        for (int r = 0; r < 16; ++r) acc[r] = sb;
#pragma unroll
        for (int t = 0; t < 9; ++t) {
            int dh = t / 3, dw = t % 3;
            int rr = r0 + dh;
            int c  = chunk * 32 + (lane & 31) + dw + 3;
            i32x4 a;
#pragma unroll
            for (int g = 0; g < 4; ++g) a[g] = smem[4 * hh + g][rr][c];
            acc = __builtin_amdgcn_mfma_i32_32x32x32_i8(a, bfrag[t], acc, 0, 0, 0);
        }
        // epilogue: requant + clamp, 4x dwordx4 stores
        int* op = out + (b * COUT + co) * HW + (ht + r0) * W_ + wt + chunk * 32 + 4 * hh;
#pragma unroll
        for (int rg = 0; rg < 4; ++rg) {
            i32x4 v;
#pragma unroll
            for (int j = 0; j < 4; ++j) {
                int t2 = (int)((unsigned)acc[rg * 4 + j] * (unsigned)isc) >> fb;
                t2 += OUT_ZP;
                v[j] = min(127, max(-128, t2));
            }
            *(i32x4*)(op + 8 * rg) = v;
        }
    }
}

extern "C" void kernel_launch(void* const* d_in, const int* in_sizes, int n_in,
                              void* d_out, int out_size, void* d_ws, size_t ws_size,
                              hipStream_t stream) {
    const int*   x   = (const int*)d_in[0];
    const int*   qw  = (const int*)d_in[1];
    const int*   qb  = (const int*)d_in[2];
    const float* wsc = (const float*)d_in[3];
    int* ws  = (int*)d_ws;
    int* out = (int*)d_out;

    qconv_prep<<<32, 256, 0, stream>>>(qw, qb, wsc, ws);
    dim3 grid(W_ / TW, H_ / TH, B_);
    qconv_main<<<grid, 256, 0, stream>>>(x, ws, out);
}

// Round 4
// 257.230 us; speedup vs baseline: 1.1306x; 1.0387x over previous
//
#include <hip/hip_runtime.h>

#define B_   16
#define CIN  32
#define COUT 32
#define H_   256
#define W_   256
#define IN_ZP  3
#define OUT_ZP (-5)
#define HW (H_ * W_)

using i32x4  = __attribute__((ext_vector_type(4))) int;
using i32x16 = __attribute__((ext_vector_type(16))) int;

typedef const __attribute__((address_space(1))) void* gptr_t;
typedef __attribute__((address_space(3))) void* lptr_t;

// ws layout (ints):
//   [0 .. 2303]    B fragments: ws[(t*64+lane)*4+g], byte b =
//                  qweight[co=lane&31][ci=16*(lane>>5)+4g+b][tap t]
//   [2304 .. 2335] shifted bias; [2336..2367] int_scale; [2368..2399] frac_bits
//   [4096 .. ]     p8: packed int8x4 x, layout [b][cig][h][w] (33.55 MB)
#define P8_OFF 4096

__global__ void qconv_prep(const int* __restrict__ qw, const int* __restrict__ qb,
                           const float* __restrict__ wscale, int* __restrict__ ws) {
    const int co  = blockIdx.x;   // 32 blocks
    const int tid = threadIdx.x;  // 256 threads
    __shared__ int red[4];
    const int* wco = qw + co * (CIN * 9);

    int s = 0;
    for (int i = tid; i < CIN * 9; i += 256) s += wco[i];
    for (int off = 32; off; off >>= 1) s += __shfl_down(s, off, 64);
    if ((tid & 63) == 0) red[tid >> 6] = s;

    if (tid < 72) {
        int gidx = blockIdx.x * 72 + tid;
        int g    = gidx & 3;
        int lane = (gidx >> 2) & 63;
        int t    = gidx >> 8;
        int wco2 = lane & 31;
        int ci0  = 16 * (lane >> 5) + 4 * g;
        const int* base = qw + wco2 * (CIN * 9);
        int b0 = base[(ci0 + 0) * 9 + t] & 0xff;
        int b1 = base[(ci0 + 1) * 9 + t] & 0xff;
        int b2 = base[(ci0 + 2) * 9 + t] & 0xff;
        int b3 = base[(ci0 + 3) * 9 + t] & 0xff;
        ws[gidx] = b0 | (b1 << 8) | (b2 << 16) | (b3 << 24);
    }
    __syncthreads();
    if (tid == 0) {
        int wsum = red[0] + red[1] + red[2] + red[3];
        ws[2304 + co] = qb[co] - wsum * IN_ZP;
        float fs = (0.02f * wscale[co]) / 0.05f;
        float fb = floorf(log2f(127.0f / fs));
        ws[2336 + co] = (int)rintf(fs * exp2f(fb));  // half-to-even, matches jnp.round
        ws[2368 + co] = (int)fb;
    }
}

// ---- pass 1: repack x (int32 NCHW) -> p8 (int8x4 planes [b][cig][h][w]) ----
__global__ __launch_bounds__(256) void qconv_pack(const int* __restrict__ x,
                                                  int* __restrict__ p8) {
    int t  = blockIdx.x * 256 + threadIdx.x;  // 2,097,152 threads, 4 ints each
    int w4 = t & 63;
    int rh = t >> 6;
    int h  = rh & 255;
    int bc = rh >> 8;                          // b*8 + cig
    const int* base = x + ((bc * 4) * H_ + h) * W_ + w4 * 4;  // b*32+cig*4 planes
    i32x4 v0 = *(const i32x4*)(base);
    i32x4 v1 = *(const i32x4*)(base + HW);
    i32x4 v2 = *(const i32x4*)(base + 2 * HW);
    i32x4 v3 = *(const i32x4*)(base + 3 * HW);
    i32x4 pk;
#pragma unroll
    for (int j = 0; j < 4; ++j)
        pk[j] = (v0[j] & 0xff) | ((v1[j] & 0xff) << 8) |
                ((v2[j] & 0xff) << 16) | (v3[j] << 24);
    *(i32x4*)(p8 + t * 4) = pk;
}

// ---- pass 2: MFMA conv over packed planes; full-W 2-row tiles ----
__global__ __launch_bounds__(256) void qconv_mfma(const int* __restrict__ p8,
                                                  const int* __restrict__ ws,
                                                  int* __restrict__ out) {
    // [cig][r][264]: data cols 4..259 <-> gw 0..255, pads at 3 and 260
    __shared__ int smem[8][4][264];
    const int ht   = blockIdx.x * 2;
    const int b    = blockIdx.y;
    const int tid  = threadIdx.x;
    const int lane = tid & 63;
    const int wv   = tid >> 6;

    // async stage: wave wv owns 8 of the 32 (cig,r) rows; 1 KB per instruction
#pragma unroll
    for (int i = 0; i < 8; ++i) {
        int idx = wv * 8 + i;
        int cig = idx >> 2, r = idx & 3;
        int gh  = ht - 1 + r;
        if ((unsigned)gh < (unsigned)H_) {
            const int* gsrc = p8 + ((b * 8 + cig) * H_ + gh) * W_ + lane * 4;
            __builtin_amdgcn_global_load_lds((gptr_t)gsrc,
                                             (lptr_t)&smem[cig][r][4 + lane * 4],
                                             16, 0, 0);
        } else {
#pragma unroll
            for (int k = 0; k < 4; ++k) smem[cig][r][4 + lane + 64 * k] = 0x03030303;
        }
    }
    if (tid < 64) {  // side pads
        int cig = tid >> 3, r = (tid >> 1) & 3;
        smem[cig][r][(tid & 1) ? 260 : 3] = 0x03030303;
    }
    __syncthreads();

    const int co = lane & 31;
    const int hh = lane >> 5;

    i32x4 bfrag[9];
    const i32x4* bws = (const i32x4*)ws;
#pragma unroll
    for (int t = 0; t < 9; ++t) bfrag[t] = bws[t * 64 + lane];

    const int sb  = ws[2304 + co];
    const int isc = ws[2336 + co];
    const int fb  = ws[2368 + co];

    // 16 M-tiles (2 rows x 8 col-chunks of 32); 4 per wave
#pragma unroll
    for (int i = 0; i < 4; ++i) {
        int mt = wv * 4 + i;
        int r0 = mt >> 3, chunk = mt & 7;
        i32x16 acc;
#pragma unroll
        for (int r = 0; r < 16; ++r) acc[r] = sb;
#pragma unroll
        for (int t = 0; t < 9; ++t) {
            int dh = t / 3, dw = t % 3;
            int rr = r0 + dh;
            int c  = 3 + chunk * 32 + (lane & 31) + dw;
            i32x4 a;
#pragma unroll
            for (int g = 0; g < 4; ++g) a[g] = smem[4 * hh + g][rr][c];
            acc = __builtin_amdgcn_mfma_i32_32x32x32_i8(a, bfrag[t], acc, 0, 0, 0);
        }
        int* op = out + (b * COUT + co) * HW + (ht + r0) * W_ + chunk * 32 + 4 * hh;
#pragma unroll
        for (int rg = 0; rg < 4; ++rg) {
            i32x4 v;
#pragma unroll
            for (int j = 0; j < 4; ++j) {
                int t2 = (int)((unsigned)acc[rg * 4 + j] * (unsigned)isc) >> fb;
                t2 += OUT_ZP;
                v[j] = min(127, max(-128, t2));
            }
            *(i32x4*)(op + 8 * rg) = v;
        }
    }
}

// ---- fallback (verified R3 path) if ws too small for p8 ----
#define TH 8
#define TW 64
#define SW 72
#define SH 10
__global__ __launch_bounds__(256) void qconv_fb(const int* __restrict__ x,
                                                const int* __restrict__ ws,
                                                int* __restrict__ out) {
    __shared__ int smem[8][SH][SW];
    const int wt = blockIdx.x * TW;
    const int ht = blockIdx.y * TH;
    const int b  = blockIdx.z;
    const int tid = threadIdx.x;
    const int* xb = x + b * (CIN * HW);
    for (int idx = tid; idx < 8 * SH * (SW / 4); idx += 256) {
        int cig = idx / (SH * 18);
        int rem = idx % (SH * 18);
        int r = rem / 18, c4 = rem % 18;
        int gh = ht - 1 + r, gw0 = wt - 4 + c4 * 4;
        int pk[4];
        if ((unsigned)gh < H_ && gw0 >= 0 && gw0 + 3 < W_) {
            const int* p = xb + (cig * 4) * HW + gh * W_ + gw0;
            i32x4 v0 = *(const i32x4*)(p);
            i32x4 v1 = *(const i32x4*)(p + HW);
            i32x4 v2 = *(const i32x4*)(p + 2 * HW);
            i32x4 v3 = *(const i32x4*)(p + 3 * HW);
#pragma unroll
            for (int j = 0; j < 4; ++j)
                pk[j] = (v0[j] & 0xff) | ((v1[j] & 0xff) << 8) |
                        ((v2[j] & 0xff) << 16) | (v3[j] << 24);
        } else {
#pragma unroll
            for (int j = 0; j < 4; ++j) {
                int gw = gw0 + j;
                int b0 = 3, b1 = 3, b2 = 3, b3 = 3;
                if ((unsigned)gh < H_ && (unsigned)gw < W_) {
                    const int* p = xb + (cig * 4) * HW + gh * W_ + gw;
                    b0 = p[0] & 0xff; b1 = p[HW] & 0xff;
                    b2 = p[2 * HW] & 0xff; b3 = p[3 * HW] & 0xff;
                }
                pk[j] = b0 | (b1 << 8) | (b2 << 16) | (b3 << 24);
            }
        }
#pragma unroll
        for (int j = 0; j < 4; ++j) smem[cig][r][c4 * 4 + j] = pk[j];
    }
    __syncthreads();
    const int lane = tid & 63, wv = tid >> 6;
    const int co = lane & 31, hh = lane >> 5;
    i32x4 bfrag[9];
    const i32x4* bws = (const i32x4*)ws;
#pragma unroll
    for (int t = 0; t < 9; ++t) bfrag[t] = bws[t * 64 + lane];
    const int sb = ws[2304 + co], isc = ws[2336 + co], fb = ws[2368 + co];
#pragma unroll
    for (int i = 0; i < 4; ++i) {
        int mt = wv * 4 + i;
        int r0 = mt >> 1, chunk = mt & 1;
        i32x16 acc;
#pragma unroll
        for (int r = 0; r < 16; ++r) acc[r] = sb;
#pragma unroll
        for (int t = 0; t < 9; ++t) {
            int dh = t / 3, dw = t % 3;
            int rr = r0 + dh;
            int c  = chunk * 32 + (lane & 31) + dw + 3;
            i32x4 a;
#pragma unroll
            for (int g = 0; g < 4; ++g) a[g] = smem[4 * hh + g][rr][c];
            acc = __builtin_amdgcn_mfma_i32_32x32x32_i8(a, bfrag[t], acc, 0, 0, 0);
        }
        int* op = out + (b * COUT + co) * HW + (ht + r0) * W_ + wt + chunk * 32 + 4 * hh;
#pragma unroll
        for (int rg = 0; rg < 4; ++rg) {
            i32x4 v;
#pragma unroll
            for (int j = 0; j < 4; ++j) {
                int t2 = (int)((unsigned)acc[rg * 4 + j] * (unsigned)isc) >> fb;
                t2 += OUT_ZP;
                v[j] = min(127, max(-128, t2));
            }
            *(i32x4*)(op + 8 * rg) = v;
        }
    }
}

extern "C" void kernel_launch(void* const* d_in, const int* in_sizes, int n_in,
                              void* d_out, int out_size, void* d_ws, size_t ws_size,
                              hipStream_t stream) {
    const int*   x   = (const int*)d_in[0];
    const int*   qw  = (const int*)d_in[1];
    const int*   qb  = (const int*)d_in[2];
    const float* wsc = (const float*)d_in[3];
    int* ws  = (int*)d_ws;
    int* out = (int*)d_out;

    qconv_prep<<<32, 256, 0, stream>>>(qw, qb, wsc, ws);

    const size_t need = (size_t)P8_OFF * 4 + (size_t)B_ * 8 * HW * 4;  // ~33.6 MB
    if (ws_size >= need) {
        int* p8 = ws + P8_OFF;
        qconv_pack<<<8192, 256, 0, stream>>>(x, p8);
        dim3 grid(H_ / 2, B_);
        qconv_mfma<<<grid, 256, 0, stream>>>(p8, ws, out);
    } else {
        dim3 grid(W_ / TW, H_ / TH, B_);
        qconv_fb<<<grid, 256, 0, stream>>>(x, ws, out);
    }
}

// Round 5
// 251.610 us; speedup vs baseline: 1.1559x; 1.0223x over previous
//
#include <hip/hip_runtime.h>

#define B_   16
#define CIN  32
#define COUT 32
#define H_   256
#define W_   256
#define IN_ZP  3
#define OUT_ZP (-5)
#define HW (H_ * W_)
#define TH 8
#define TW 64
#define SW 72   // staged cols: gw = wt-4 .. wt+67
#define SH 10   // staged rows: gh = ht-1 .. ht+8

using i32x4  = __attribute__((ext_vector_type(4))) int;
using i32x16 = __attribute__((ext_vector_type(16))) int;

// ws layout (ints):
//   [0 .. 2303]    B fragments: ws[(t*64+lane)*4+g], byte b =
//                  qweight[co=lane&31][ci=16*(lane>>5)+4g+b][tap t]
//   [2304 .. 2335] shifted bias; [2336..2367] int_scale; [2368..2399] frac_bits
__global__ void qconv_prep(const int* __restrict__ qw, const int* __restrict__ qb,
                           const float* __restrict__ wscale, int* __restrict__ ws) {
    const int co  = blockIdx.x;   // 32 blocks
    const int tid = threadIdx.x;  // 256 threads
    __shared__ int red[4];
    const int* wco = qw + co * (CIN * 9);

    int s = 0;
    for (int i = tid; i < CIN * 9; i += 256) s += wco[i];
    for (int off = 32; off; off >>= 1) s += __shfl_down(s, off, 64);
    if ((tid & 63) == 0) red[tid >> 6] = s;

    if (tid < 72) {
        int gidx = blockIdx.x * 72 + tid;
        int g    = gidx & 3;
        int lane = (gidx >> 2) & 63;
        int t    = gidx >> 8;
        int wco2 = lane & 31;
        int ci0  = 16 * (lane >> 5) + 4 * g;
        const int* base = qw + wco2 * (CIN * 9);
        int b0 = base[(ci0 + 0) * 9 + t] & 0xff;
        int b1 = base[(ci0 + 1) * 9 + t] & 0xff;
        int b2 = base[(ci0 + 2) * 9 + t] & 0xff;
        int b3 = base[(ci0 + 3) * 9 + t] & 0xff;
        ws[gidx] = b0 | (b1 << 8) | (b2 << 16) | (b3 << 24);
    }
    __syncthreads();
    if (tid == 0) {
        int wsum = red[0] + red[1] + red[2] + red[3];
        ws[2304 + co] = qb[co] - wsum * IN_ZP;
        float fs = (0.02f * wscale[co]) / 0.05f;
        float fb = floorf(log2f(127.0f / fs));
        ws[2336 + co] = (int)rintf(fs * exp2f(fb));  // half-to-even, matches jnp.round
        ws[2368 + co] = (int)fb;
    }
}

// branch-free staging of one packed item (clamped loads + select for pad)
__device__ __forceinline__ void stage_item(int idx, int ht, int wt,
                                           const int* __restrict__ xb,
                                           int (*smem)[SH][SW]) {
    int cig = idx / 180;
    int rem = idx - cig * 180;
    int r   = rem / 18;
    int c4  = rem - r * 18;
    int gh  = ht - 1 + r;
    int gw0 = wt - 4 + c4 * 4;
    int ghc = min(H_ - 1, max(0, gh));
    int gwc = min(W_ - 4, max(0, gw0));
    const int* p = xb + (cig * 4) * HW + ghc * W_ + gwc;
    i32x4 v0 = *(const i32x4*)(p);
    i32x4 v1 = *(const i32x4*)(p + HW);
    i32x4 v2 = *(const i32x4*)(p + 2 * HW);
    i32x4 v3 = *(const i32x4*)(p + 3 * HW);
    bool vh = (unsigned)gh < (unsigned)H_;
    i32x4 pk;
#pragma unroll
    for (int j = 0; j < 4; ++j) {
        int t = (v0[j] & 0xff) | ((v1[j] & 0xff) << 8) |
                ((v2[j] & 0xff) << 16) | (v3[j] << 24);
        bool ok = vh && ((unsigned)(gw0 + j) < (unsigned)W_);
        pk[j] = ok ? t : 0x03030303;
    }
    *(i32x4*)&smem[cig][r][c4 * 4] = pk;
}

__global__ __launch_bounds__(256) void qconv_fused(const int* __restrict__ x,
                                                   const int* __restrict__ ws,
                                                   int* __restrict__ out) {
    __shared__ int smem[8][SH][SW];        // packed int8x4 im2col tile (23 KB)
    __shared__ int scr[4][33 * 32];        // per-wave epilogue transpose (16.5 KB)
    const int wt = blockIdx.x * TW;
    const int ht = blockIdx.y * TH;
    const int b  = blockIdx.z;
    const int tid = threadIdx.x;
    const int* xb = x + b * (CIN * HW);

    // ---- staging: 1440 items, 6 per thread, straight-line & branch-free ----
    stage_item(tid,        ht, wt, xb, smem);
    stage_item(tid + 256,  ht, wt, xb, smem);
    stage_item(tid + 512,  ht, wt, xb, smem);
    stage_item(tid + 768,  ht, wt, xb, smem);
    stage_item(tid + 1024, ht, wt, xb, smem);
    if (tid < 160) stage_item(tid + 1280, ht, wt, xb, smem);
    __syncthreads();

    const int lane = tid & 63, wv = tid >> 6;
    const int co = lane & 31, hh = lane >> 5;

    i32x4 bfrag[9];
    const i32x4* bws = (const i32x4*)ws;
#pragma unroll
    for (int t = 0; t < 9; ++t) bfrag[t] = bws[t * 64 + lane];

    const int sb  = ws[2304 + co];
    const int isc = ws[2336 + co];
    const int fb  = ws[2368 + co];

    int* myscr = &scr[wv][0];
    const int w_r   = lane & 31;   // epilogue read lane mapping
    const int cbase = lane >> 5;

    // 16 M-tiles (8 rows x 2 col-chunks of 32); 4 per wave
#pragma unroll
    for (int i = 0; i < 4; ++i) {
        int mt = wv * 4 + i;
        int r0 = mt >> 1, chunk = mt & 1;
        i32x16 acc;
#pragma unroll
        for (int r = 0; r < 16; ++r) acc[r] = sb;
#pragma unroll
        for (int t = 0; t < 9; ++t) {
            int dh = t / 3, dw = t % 3;
            int rr = r0 + dh;
            int c  = chunk * 32 + (lane & 31) + dw + 3;
            i32x4 a;
#pragma unroll
            for (int g = 0; g < 4; ++g) a[g] = smem[4 * hh + g][rr][c];
            acc = __builtin_amdgcn_mfma_i32_32x32x32_i8(a, bfrag[t], acc, 0, 0, 0);
        }
        // requant into per-wave LDS scratch ([co][33] pad -> conflict-free)
#pragma unroll
        for (int rg = 0; rg < 4; ++rg)
#pragma unroll
            for (int j = 0; j < 4; ++j) {
                int t2 = (int)((unsigned)acc[rg * 4 + j] * (unsigned)isc) >> fb;
                t2 += OUT_ZP;
                t2 = min(127, max(-128, t2));
                myscr[co * 33 + (4 * hh + 8 * rg + j)] = t2;
            }
        // transposed read-back -> coalesced 256B stores (2 x 128B segments)
        int* op = out + (b * COUT) * HW + (ht + r0) * W_ + wt + chunk * 32 + w_r;
#pragma unroll
        for (int it = 0; it < 16; ++it) {
            int co_r = 2 * it + cbase;
            op[co_r * HW] = myscr[co_r * 33 + w_r];
        }
    }
}

extern "C" void kernel_launch(void* const* d_in, const int* in_sizes, int n_in,
                              void* d_out, int out_size, void* d_ws, size_t ws_size,
                              hipStream_t stream) {
    const int*   x   = (const int*)d_in[0];
    const int*   qw  = (const int*)d_in[1];
    const int*   qb  = (const int*)d_in[2];
    const float* wsc = (const float*)d_in[3];
    int* ws  = (int*)d_ws;
    int* out = (int*)d_out;

    qconv_prep<<<32, 256, 0, stream>>>(qw, qb, wsc, ws);
    dim3 grid(W_ / TW, H_ / TH, B_);
    qconv_fused<<<grid, 256, 0, stream>>>(x, ws, out);
}